// Round 1
// baseline (499.537 us; speedup 1.0000x reference)
//
#include <hip/hip_runtime.h>
#include <hip/hip_bf16.h>

#define B_SZ 16384
#define F_SZ 2048
#define D_SZ 256
#define E_SZ 8

typedef __attribute__((ext_vector_type(8))) short bhalf8;
typedef __attribute__((ext_vector_type(4))) float fl4;

__device__ __forceinline__ short f2b(float f) {
  __hip_bfloat16 h = __float2bfloat16(f);
  union { __hip_bfloat16 h; short s; } u;
  u.h = h;
  return u.s;
}

// ---------------- bucket kernels ----------------
__global__ void k_zero(int* counts) {
  if (threadIdx.x < E_SZ) counts[threadIdx.x] = 0;
}

__global__ void k_scatter(const int* __restrict__ ids, int* __restrict__ counts,
                          int* __restrict__ perm) {
  __shared__ int lcnt[E_SZ], lbase[E_SZ];
  int t = threadIdx.x;
  if (t < E_SZ) lcnt[t] = 0;
  __syncthreads();
  int b = blockIdx.x * 256 + t;
  int e = ids[b];
  int p = atomicAdd(&lcnt[e], 1);
  __syncthreads();
  if (t < E_SZ) lbase[t] = atomicAdd(&counts[t], lcnt[t]);
  __syncthreads();
  perm[e * B_SZ + lbase[e] + p] = b;
}

// ---------------- W transpose+cast: Wt[e][d][f] = bf16(W[e][f][d]) ----------------
__global__ void k_transpose(const float* __restrict__ W, __hip_bfloat16* __restrict__ Wt) {
  __shared__ float tile[64][65];
  int e = blockIdx.z;
  int f0 = blockIdx.x * 64;
  int d0 = blockIdx.y * 64;
  int t = threadIdx.x;
  const float* src = W + ((size_t)e * F_SZ + f0) * D_SZ + d0;
  int fr = t >> 2, c0 = t & 3;
#pragma unroll
  for (int c = c0; c < 16; c += 4) {
    float4 v = *(const float4*)(src + (size_t)fr * D_SZ + c * 4);
    tile[fr][c * 4 + 0] = v.x;
    tile[fr][c * 4 + 1] = v.y;
    tile[fr][c * 4 + 2] = v.z;
    tile[fr][c * 4 + 3] = v.w;
  }
  __syncthreads();
  int dr = t >> 2, cc = t & 3;
  union { unsigned short u[16]; bhalf8 v[2]; } pk;
#pragma unroll
  for (int k = 0; k < 16; ++k) pk.u[k] = (unsigned short)f2b(tile[cc * 16 + k][dr]);
  __hip_bfloat16* dst = Wt + ((size_t)e * D_SZ + d0 + dr) * F_SZ + f0 + cc * 16;
  ((bhalf8*)dst)[0] = pk.v[0];
  ((bhalf8*)dst)[1] = pk.v[1];
}

// ---------------- async 16B global -> LDS ----------------
__device__ __forceinline__ void load_lds16(const __hip_bfloat16* g, __hip_bfloat16* l) {
  __builtin_amdgcn_global_load_lds((const __attribute__((address_space(1))) void*)g,
                                   (__attribute__((address_space(3))) void*)l, 16, 0, 0);
}

// ---------------- gather GEMM: out[perm[m]] = bf16(x[perm[m]]) @ Wt[e]^T + b[e] ----------------
__launch_bounds__(256, 2)
__global__ void k_gemm(const float* __restrict__ x, const __hip_bfloat16* __restrict__ Wt,
                       const float* __restrict__ bias, const int* __restrict__ counts,
                       const int* __restrict__ perm, float* __restrict__ out) {
  int e = blockIdx.z;
  int count = counts[e];
  int mbase = blockIdx.x * 128;
  if (mbase >= count) return;
  int nb = blockIdx.y * 128;

  // Bs chunk layout: chunk index s = kc*128 + n (16B = 8 bf16 of k), kc in [0,4), n in [0,128)
  __shared__ __align__(16) __hip_bfloat16 Bs[4 * 128 * 8];

  int t = threadIdx.x;
  int w = t >> 6;       // wave id 0..3
  int lane = t & 63;
  int wm = w >> 1, wn = w & 1;
  int l15 = lane & 15;
  int q = lane >> 4;

  const int* permE = perm + e * B_SZ;
  const float* pA[4];
#pragma unroll
  for (int i = 0; i < 4; ++i) {
    int gm = mbase + wm * 64 + i * 16 + l15;
    int src = permE[(gm < count) ? gm : mbase];   // dummy row for ragged tail
    pA[i] = x + (size_t)src * F_SZ + q * 8;       // A frag: m=lane&15, k=q*8+j
  }

  fl4 zz = {0.0f, 0.0f, 0.0f, 0.0f};
  fl4 acc[4][4];
#pragma unroll
  for (int i = 0; i < 4; ++i)
#pragma unroll
    for (int j = 0; j < 4; ++j) acc[i][j] = zz;

  // staging sources: chunk s = c*256 + t -> kc = s>>7, n = s&127
  int n_ = t & 127;
  int kc_ = t >> 7;
  const __hip_bfloat16* g0 = Wt + (size_t)(e * D_SZ + nb + n_) * F_SZ + kc_ * 8;
  const __hip_bfloat16* g1 = g0 + 16;  // kc_+2, same n
  __hip_bfloat16* ldst0 = Bs + (size_t)(w * 64) * 8;          // wave-uniform LDS base
  __hip_bfloat16* ldst1 = Bs + (size_t)(256 + w * 64) * 8;

  for (int k0 = 0; k0 < F_SZ; k0 += 32) {
    __syncthreads();                 // previous iter's ds_reads done before overwrite
    load_lds16(g0 + k0, ldst0);
    load_lds16(g1 + k0, ldst1);
    __syncthreads();                 // drains vmcnt -> Bs valid

    bhalf8 af[4];
#pragma unroll
    for (int i = 0; i < 4; ++i) {
      float4 u0 = *(const float4*)(pA[i] + k0);
      float4 u1 = *(const float4*)(pA[i] + k0 + 4);
      bhalf8 v;
      v[0] = f2b(u0.x); v[1] = f2b(u0.y); v[2] = f2b(u0.z); v[3] = f2b(u0.w);
      v[4] = f2b(u1.x); v[5] = f2b(u1.y); v[6] = f2b(u1.z); v[7] = f2b(u1.w);
      af[i] = v;
    }
    bhalf8 bfr[4];
#pragma unroll
    for (int j = 0; j < 4; ++j) {
      int chunk = q * 128 + wn * 64 + j * 16 + l15;   // kc=q, n=wn*64+j*16+l15
      bfr[j] = *(const bhalf8*)(Bs + (size_t)chunk * 8);
    }
#pragma unroll
    for (int i = 0; i < 4; ++i)
#pragma unroll
      for (int j = 0; j < 4; ++j)
        acc[i][j] = __builtin_amdgcn_mfma_f32_16x16x32_bf16(af[i], bfr[j], acc[i][j], 0, 0, 0);
  }

  // epilogue: C/D layout col = lane&15, row = q*4 + reg
  float bv[4];
#pragma unroll
  for (int j = 0; j < 4; ++j) bv[j] = bias[e * D_SZ + nb + wn * 64 + j * 16 + l15];

#pragma unroll
  for (int i = 0; i < 4; ++i) {
#pragma unroll
    for (int r = 0; r < 4; ++r) {
      int gm = mbase + wm * 64 + i * 16 + q * 4 + r;
      if (gm < count) {
        int row = permE[gm];
        float* po = out + (size_t)row * D_SZ + nb + wn * 64;
#pragma unroll
        for (int j = 0; j < 4; ++j) po[j * 16 + l15] = acc[i][j][r] + bv[j];
      }
    }
  }
}

extern "C" void kernel_launch(void* const* d_in, const int* in_sizes, int n_in,
                              void* d_out, int out_size, void* d_ws, size_t ws_size,
                              hipStream_t stream) {
  const float* x = (const float*)d_in[0];
  const float* W = (const float*)d_in[1];
  const float* bias = (const float*)d_in[2];
  const int* ids = (const int*)d_in[3];
  float* out = (float*)d_out;

  char* ws = (char*)d_ws;
  int* counts = (int*)ws;                               // 32 B
  int* perm = (int*)(ws + 256);                         // 512 KB
  __hip_bfloat16* Wt = (__hip_bfloat16*)(ws + (1 << 20)); // 8 MB

  k_zero<<<1, 64, 0, stream>>>(counts);
  k_scatter<<<B_SZ / 256, 256, 0, stream>>>(ids, counts, perm);
  k_transpose<<<dim3(F_SZ / 64, D_SZ / 64, E_SZ), 256, 0, stream>>>(W, Wt);
  k_gemm<<<dim3(B_SZ / 128, D_SZ / 128, E_SZ), 256, 0, stream>>>(x, Wt, bias, counts, perm, out);
}

// Round 2
// 471.967 us; speedup vs baseline: 1.0584x; 1.0584x over previous
//
#include <hip/hip_runtime.h>
#include <hip/hip_bf16.h>

#define B_SZ 16384
#define F_SZ 2048
#define D_SZ 256
#define E_SZ 8

typedef __attribute__((ext_vector_type(8))) short bhalf8;
typedef __attribute__((ext_vector_type(4))) float fl4;

__device__ __forceinline__ short f2b(float f) {
  __hip_bfloat16 h = __float2bfloat16(f);
  union { __hip_bfloat16 h; short s; } u;
  u.h = h;
  return u.s;
}

// ---------------- bucket kernels ----------------
__global__ void k_zero(int* counts) {
  if (threadIdx.x < E_SZ) counts[threadIdx.x] = 0;
}

__global__ void k_scatter(const int* __restrict__ ids, int* __restrict__ counts,
                          int* __restrict__ perm) {
  __shared__ int lcnt[E_SZ], lbase[E_SZ];
  int t = threadIdx.x;
  if (t < E_SZ) lcnt[t] = 0;
  __syncthreads();
  int b = blockIdx.x * 256 + t;
  int e = ids[b];
  int p = atomicAdd(&lcnt[e], 1);
  __syncthreads();
  if (t < E_SZ) lbase[t] = atomicAdd(&counts[t], lcnt[t]);
  __syncthreads();
  perm[e * B_SZ + lbase[e] + p] = b;
}

// ---------------- W transpose+cast: Wt[e][d][f] = bf16(W[e][f][d]) ----------------
__global__ void k_transpose(const float* __restrict__ W, __hip_bfloat16* __restrict__ Wt) {
  __shared__ float tile[64][65];
  int e = blockIdx.z;
  int f0 = blockIdx.x * 64;
  int d0 = blockIdx.y * 64;
  int t = threadIdx.x;
  const float* src = W + ((size_t)e * F_SZ + f0) * D_SZ + d0;
  int fr = t >> 2, c0 = t & 3;
#pragma unroll
  for (int c = c0; c < 16; c += 4) {
    float4 v = *(const float4*)(src + (size_t)fr * D_SZ + c * 4);
    tile[fr][c * 4 + 0] = v.x;
    tile[fr][c * 4 + 1] = v.y;
    tile[fr][c * 4 + 2] = v.z;
    tile[fr][c * 4 + 3] = v.w;
  }
  __syncthreads();
  int dr = t >> 2, cc = t & 3;
  union { unsigned short u[16]; bhalf8 v[2]; } pk;
#pragma unroll
  for (int k = 0; k < 16; ++k) pk.u[k] = (unsigned short)f2b(tile[cc * 16 + k][dr]);
  __hip_bfloat16* dst = Wt + ((size_t)e * D_SZ + d0 + dr) * F_SZ + f0 + cc * 16;
  ((bhalf8*)dst)[0] = pk.v[0];
  ((bhalf8*)dst)[1] = pk.v[1];
}

// ---------------- async 16B global -> LDS ----------------
__device__ __forceinline__ void load_lds16(const __hip_bfloat16* g, __hip_bfloat16* l) {
  __builtin_amdgcn_global_load_lds((const __attribute__((address_space(1))) void*)g,
                                   (__attribute__((address_space(3))) void*)l, 16, 0, 0);
}

// ---------------- gather GEMM: out[perm[m]] = bf16(x[perm[m]]) @ Wt[e]^T + b[e] ----------------
// BM=64 (2 blocks/CU for latency hiding), BN=128, BK=32; 4 waves in 2x2, wave tile 32x64.
__launch_bounds__(256, 4)
__global__ void k_gemm(const float* __restrict__ x, const __hip_bfloat16* __restrict__ Wt,
                       const float* __restrict__ bias, const int* __restrict__ counts,
                       const int* __restrict__ perm, float* __restrict__ out) {
  int e = blockIdx.z;
  int count = counts[e];
  int mbase = blockIdx.x * 64;
  if (mbase >= count) return;
  int nb = blockIdx.y * 128;

  // Bs chunk layout: chunk index s = kc*128 + n (16B = 8 bf16 of k), kc in [0,4), n in [0,128)
  __shared__ __align__(16) __hip_bfloat16 Bs[4 * 128 * 8];

  int t = threadIdx.x;
  int w = t >> 6;       // wave id 0..3
  int lane = t & 63;
  int wm = w >> 1, wn = w & 1;
  int l15 = lane & 15;
  int q = lane >> 4;

  const int* permE = perm + e * B_SZ;
  const float* pA[2];
#pragma unroll
  for (int i = 0; i < 2; ++i) {
    int gm = mbase + wm * 32 + i * 16 + l15;
    int src = permE[(gm < count) ? gm : mbase];   // dummy row for ragged tail
    pA[i] = x + (size_t)src * F_SZ + q * 8;       // A frag: m=lane&15, k=q*8+j
  }

  fl4 zz = {0.0f, 0.0f, 0.0f, 0.0f};
  fl4 acc[2][4];
#pragma unroll
  for (int i = 0; i < 2; ++i)
#pragma unroll
    for (int j = 0; j < 4; ++j) acc[i][j] = zz;

  // staging sources: chunk s = c*256 + t -> kc = s>>7, n = s&127
  int n_ = t & 127;
  int kc_ = t >> 7;
  const __hip_bfloat16* g0 = Wt + (size_t)(e * D_SZ + nb + n_) * F_SZ + kc_ * 8;
  const __hip_bfloat16* g1 = g0 + 16;  // kc_+2, same n
  __hip_bfloat16* ldst0 = Bs + (size_t)(w * 64) * 8;          // wave-uniform LDS base
  __hip_bfloat16* ldst1 = Bs + (size_t)(256 + w * 64) * 8;

  for (int k0 = 0; k0 < F_SZ; k0 += 32) {
    __syncthreads();                 // previous iter's ds_reads done before overwrite
    load_lds16(g0 + k0, ldst0);
    load_lds16(g1 + k0, ldst1);
    __syncthreads();                 // drains vmcnt -> Bs valid

    bhalf8 af[2];
#pragma unroll
    for (int i = 0; i < 2; ++i) {
      float4 u0 = *(const float4*)(pA[i] + k0);
      float4 u1 = *(const float4*)(pA[i] + k0 + 4);
      bhalf8 v;
      v[0] = f2b(u0.x); v[1] = f2b(u0.y); v[2] = f2b(u0.z); v[3] = f2b(u0.w);
      v[4] = f2b(u1.x); v[5] = f2b(u1.y); v[6] = f2b(u1.z); v[7] = f2b(u1.w);
      af[i] = v;
    }
    bhalf8 bfr[4];
#pragma unroll
    for (int j = 0; j < 4; ++j) {
      int chunk = q * 128 + wn * 64 + j * 16 + l15;   // kc=q, n=wn*64+j*16+l15
      bfr[j] = *(const bhalf8*)(Bs + (size_t)chunk * 8);
    }
#pragma unroll
    for (int i = 0; i < 2; ++i)
#pragma unroll
      for (int j = 0; j < 4; ++j)
        acc[i][j] = __builtin_amdgcn_mfma_f32_16x16x32_bf16(af[i], bfr[j], acc[i][j], 0, 0, 0);
  }

  // epilogue: C/D layout col = lane&15, row = q*4 + reg
  float bv[4];
#pragma unroll
  for (int j = 0; j < 4; ++j) bv[j] = bias[e * D_SZ + nb + wn * 64 + j * 16 + l15];

#pragma unroll
  for (int i = 0; i < 2; ++i) {
#pragma unroll
    for (int r = 0; r < 4; ++r) {
      int gm = mbase + wm * 32 + i * 16 + q * 4 + r;
      if (gm < count) {
        int row = permE[gm];
        float* po = out + (size_t)row * D_SZ + nb + wn * 64;
#pragma unroll
        for (int j = 0; j < 4; ++j) po[j * 16 + l15] = acc[i][j][r] + bv[j];
      }
    }
  }
}

extern "C" void kernel_launch(void* const* d_in, const int* in_sizes, int n_in,
                              void* d_out, int out_size, void* d_ws, size_t ws_size,
                              hipStream_t stream) {
  const float* x = (const float*)d_in[0];
  const float* W = (const float*)d_in[1];
  const float* bias = (const float*)d_in[2];
  const int* ids = (const int*)d_in[3];
  float* out = (float*)d_out;

  char* ws = (char*)d_ws;
  int* counts = (int*)ws;                               // 32 B
  int* perm = (int*)(ws + 256);                         // 512 KB
  __hip_bfloat16* Wt = (__hip_bfloat16*)(ws + (1 << 20)); // 8 MB

  k_zero<<<1, 64, 0, stream>>>(counts);
  k_scatter<<<B_SZ / 256, 256, 0, stream>>>(ids, counts, perm);
  k_transpose<<<dim3(F_SZ / 64, D_SZ / 64, E_SZ), 256, 0, stream>>>(W, Wt);
  k_gemm<<<dim3(B_SZ / 64, D_SZ / 128, E_SZ), 256, 0, stream>>>(x, Wt, bias, counts, perm, out);
}

// Round 3
// 357.128 us; speedup vs baseline: 1.3988x; 1.3216x over previous
//
#include <hip/hip_runtime.h>
#include <hip/hip_bf16.h>

#define B_SZ 16384
#define F_SZ 2048
#define D_SZ 256
#define E_SZ 8
#define MAX_MT 264              // max total m-tiles: sum ceil(count_e/64) <= 256+8
#define GRID_G (MAX_MT * 2)     // x2 n-tiles

typedef __attribute__((ext_vector_type(8))) short bhalf8;
typedef __attribute__((ext_vector_type(4))) float fl4;

__device__ __forceinline__ short f2b(float f) {
  __hip_bfloat16 h = __float2bfloat16(f);
  union { __hip_bfloat16 h; short s; } u;
  u.h = h;
  return u.s;
}

// ---------------- bucket kernels ----------------
__global__ void k_zero(int* counts) {
  if (threadIdx.x < E_SZ) counts[threadIdx.x] = 0;
}

__global__ void k_scatter(const int* __restrict__ ids, int* __restrict__ counts,
                          int* __restrict__ perm) {
  __shared__ int lcnt[E_SZ], lbase[E_SZ];
  int t = threadIdx.x;
  if (t < E_SZ) lcnt[t] = 0;
  __syncthreads();
  int b = blockIdx.x * 256 + t;
  int e = ids[b];
  int p = atomicAdd(&lcnt[e], 1);
  __syncthreads();
  if (t < E_SZ) lbase[t] = atomicAdd(&counts[t], lcnt[t]);
  __syncthreads();
  perm[e * B_SZ + lbase[e] + p] = b;
}

// ---------------- W transpose+cast: Wt[e][d][f] = bf16(W[e][f][d]) ----------------
__global__ void k_transpose(const float* __restrict__ W, __hip_bfloat16* __restrict__ Wt) {
  __shared__ float tile[64][65];
  int e = blockIdx.z;
  int f0 = blockIdx.x * 64;
  int d0 = blockIdx.y * 64;
  int t = threadIdx.x;
  const float* src = W + ((size_t)e * F_SZ + f0) * D_SZ + d0;
  int fr = t >> 2, c0 = t & 3;
#pragma unroll
  for (int c = c0; c < 16; c += 4) {
    float4 v = *(const float4*)(src + (size_t)fr * D_SZ + c * 4);
    tile[fr][c * 4 + 0] = v.x;
    tile[fr][c * 4 + 1] = v.y;
    tile[fr][c * 4 + 2] = v.z;
    tile[fr][c * 4 + 3] = v.w;
  }
  __syncthreads();
  int dr = t >> 2, cc = t & 3;
  union { unsigned short u[16]; bhalf8 v[2]; } pk;
#pragma unroll
  for (int k = 0; k < 16; ++k) pk.u[k] = (unsigned short)f2b(tile[cc * 16 + k][dr]);
  __hip_bfloat16* dst = Wt + ((size_t)e * D_SZ + d0 + dr) * F_SZ + f0 + cc * 16;
  ((bhalf8*)dst)[0] = pk.v[0];
  ((bhalf8*)dst)[1] = pk.v[1];
}

// ---------------- async 16B global -> LDS ----------------
__device__ __forceinline__ void load_lds16(const __hip_bfloat16* g, __hip_bfloat16* l) {
  __builtin_amdgcn_global_load_lds((const __attribute__((address_space(1))) void*)g,
                                   (__attribute__((address_space(3))) void*)l, 16, 0, 0);
}

// ---------------- gather GEMM, flattened 1-D grid ----------------
// BM=64, BN=128, BK=32; 4 waves 2x2, wave tile 32x64.
// LDS double-buffer + register A-prefetch: ONE barrier per K-iter.
__launch_bounds__(256, 4)
__global__ void k_gemm(const float* __restrict__ x, const __hip_bfloat16* __restrict__ Wt,
                       const float* __restrict__ bias, const int* __restrict__ counts,
                       const int* __restrict__ perm, float* __restrict__ out) {
  // ---- flattened work decode: id -> (expert e, mbase, nb) ----
  int id = blockIdx.x;
  int nb = (id & 1) * 128;
  int mt = id >> 1;
  int e = -1, mbase = 0, count = 0;
  {
    int acc = 0;
#pragma unroll
    for (int ee = 0; ee < E_SZ; ++ee) {
      int c = counts[ee];
      int nt = (c + 63) >> 6;
      if (e < 0 && mt < acc + nt) { e = ee; mbase = (mt - acc) * 64; count = c; }
      acc += nt;
    }
  }
  if (e < 0) return;

  // Bs chunk layout per buffer: chunk s = kc*128 + n (16B = 8 bf16 of k), kc in [0,4)
  __shared__ __align__(16) __hip_bfloat16 Bs[2][4 * 128 * 8];

  int t = threadIdx.x;
  int w = t >> 6;
  int lane = t & 63;
  int wm = w >> 1, wn = w & 1;
  int l15 = lane & 15;
  int q = lane >> 4;

  const int* permE = perm + e * B_SZ;
  const float* pA[2];
#pragma unroll
  for (int i = 0; i < 2; ++i) {
    int gm = mbase + wm * 32 + i * 16 + l15;
    int src = permE[(gm < count) ? gm : mbase];   // dummy row for ragged tail
    pA[i] = x + (size_t)src * F_SZ + q * 8;       // A frag: m=lane&15, k=q*8+j
  }

  fl4 zz = {0.0f, 0.0f, 0.0f, 0.0f};
  fl4 acc[2][4];
#pragma unroll
  for (int i = 0; i < 2; ++i)
#pragma unroll
    for (int j = 0; j < 4; ++j) acc[i][j] = zz;

  // staging: thread t stages chunk t (kc=t>>7, n=t&127) and chunk t+256
  int n_ = t & 127;
  int kc_ = t >> 7;
  const __hip_bfloat16* g0 = Wt + (size_t)(e * D_SZ + nb + n_) * F_SZ + kc_ * 8;
  const __hip_bfloat16* g1 = g0 + 16;   // kc_+2, same n
  int ldso0 = (w * 64) * 8;             // wave-uniform element offsets within a buffer
  int ldso1 = (256 + w * 64) * 8;

  // ---- prologue: stage k0=0 into buf 0, prefetch A(0) into regs ----
  load_lds16(g0, &Bs[0][ldso0]);
  load_lds16(g1, &Bs[0][ldso1]);
  float4 ca[2][2];
#pragma unroll
  for (int i = 0; i < 2; ++i) {
    ca[i][0] = *(const float4*)(pA[i]);
    ca[i][1] = *(const float4*)(pA[i] + 4);
  }
  __syncthreads();   // drains vmcnt: buf0 + A(0) ready

  int p = 0;
  for (int k0 = 0; k0 < F_SZ; k0 += 32) {
    int kn = k0 + 32;
    float4 na[2][2];
    if (kn < F_SZ) {
      // prefetch next B tile into other buffer + next A into regs
      load_lds16(g0 + kn, &Bs[p ^ 1][ldso0]);
      load_lds16(g1 + kn, &Bs[p ^ 1][ldso1]);
#pragma unroll
      for (int i = 0; i < 2; ++i) {
        na[i][0] = *(const float4*)(pA[i] + kn);
        na[i][1] = *(const float4*)(pA[i] + kn + 4);
      }
    }

    // compute current tile from buf p / regs ca
    bhalf8 af[2];
#pragma unroll
    for (int i = 0; i < 2; ++i) {
      bhalf8 v;
      v[0] = f2b(ca[i][0].x); v[1] = f2b(ca[i][0].y);
      v[2] = f2b(ca[i][0].z); v[3] = f2b(ca[i][0].w);
      v[4] = f2b(ca[i][1].x); v[5] = f2b(ca[i][1].y);
      v[6] = f2b(ca[i][1].z); v[7] = f2b(ca[i][1].w);
      af[i] = v;
    }
    bhalf8 bfr[4];
#pragma unroll
    for (int j = 0; j < 4; ++j) {
      int chunk = q * 128 + wn * 64 + j * 16 + l15;   // kc=q, n=wn*64+j*16+l15
      bfr[j] = *(const bhalf8*)(&Bs[p][chunk * 8]);
    }
#pragma unroll
    for (int i = 0; i < 2; ++i)
#pragma unroll
      for (int j = 0; j < 4; ++j)
        acc[i][j] = __builtin_amdgcn_mfma_f32_16x16x32_bf16(af[i], bfr[j], acc[i][j], 0, 0, 0);

    __syncthreads();   // drains prefetch vm + this iter's ds_reads; buf p^1 valid next iter
#pragma unroll
    for (int i = 0; i < 2; ++i) {
      ca[i][0] = na[i][0];
      ca[i][1] = na[i][1];
    }
    p ^= 1;
  }

  // epilogue: C/D layout col = lane&15, row = q*4 + reg
  float bv[4];
#pragma unroll
  for (int j = 0; j < 4; ++j) bv[j] = bias[e * D_SZ + nb + wn * 64 + j * 16 + l15];

#pragma unroll
  for (int i = 0; i < 2; ++i) {
#pragma unroll
    for (int r = 0; r < 4; ++r) {
      int gm = mbase + wm * 32 + i * 16 + q * 4 + r;
      if (gm < count) {
        int row = permE[gm];
        float* po = out + (size_t)row * D_SZ + nb + wn * 64;
#pragma unroll
        for (int j = 0; j < 4; ++j) po[j * 16 + l15] = acc[i][j][r] + bv[j];
      }
    }
  }
}

extern "C" void kernel_launch(void* const* d_in, const int* in_sizes, int n_in,
                              void* d_out, int out_size, void* d_ws, size_t ws_size,
                              hipStream_t stream) {
  const float* x = (const float*)d_in[0];
  const float* W = (const float*)d_in[1];
  const float* bias = (const float*)d_in[2];
  const int* ids = (const int*)d_in[3];
  float* out = (float*)d_out;

  char* ws = (char*)d_ws;
  int* counts = (int*)ws;                                 // 32 B
  int* perm = (int*)(ws + 256);                           // 512 KB
  __hip_bfloat16* Wt = (__hip_bfloat16*)(ws + (1 << 20)); // 8 MB

  k_zero<<<1, 64, 0, stream>>>(counts);
  k_scatter<<<B_SZ / 256, 256, 0, stream>>>(ids, counts, perm);
  k_transpose<<<dim3(F_SZ / 64, D_SZ / 64, E_SZ), 256, 0, stream>>>(W, Wt);
  k_gemm<<<GRID_G, 256, 0, stream>>>(x, Wt, bias, counts, perm, out);
}

// Round 4
// 342.096 us; speedup vs baseline: 1.4602x; 1.0439x over previous
//
#include <hip/hip_runtime.h>
#include <hip/hip_bf16.h>

#define B_SZ 16384
#define F_SZ 2048
#define D_SZ 256
#define E_SZ 8
#define GRID_G 520   // max m-tiles: sum_e ceil(count_e/32) <= 512 + 8

typedef __attribute__((ext_vector_type(8))) short bhalf8;
typedef __attribute__((ext_vector_type(4))) float fl4;

__device__ __forceinline__ short f2b(float f) {
  __hip_bfloat16 h = __float2bfloat16(f);
  union { __hip_bfloat16 h; short s; } u;
  u.h = h;
  return u.s;
}

// ---------------- bucket scatter ----------------
__global__ void k_scatter(const int* __restrict__ ids, int* __restrict__ counts,
                          int* __restrict__ perm) {
  __shared__ int lcnt[E_SZ], lbase[E_SZ];
  int t = threadIdx.x;
  if (t < E_SZ) lcnt[t] = 0;
  __syncthreads();
  int b = blockIdx.x * 256 + t;
  int e = ids[b];
  int p = atomicAdd(&lcnt[e], 1);
  __syncthreads();
  if (t < E_SZ) lbase[t] = atomicAdd(&counts[t], lcnt[t]);
  __syncthreads();
  perm[e * B_SZ + lbase[e] + p] = b;
}

// ---------------- W transpose+cast: Wt[e][d][f] = bf16(W[e][f][d]) ----------------
__global__ void k_transpose(const float* __restrict__ W, __hip_bfloat16* __restrict__ Wt) {
  __shared__ float tile[64][65];
  int e = blockIdx.z;
  int f0 = blockIdx.x * 64;
  int d0 = blockIdx.y * 64;
  int t = threadIdx.x;
  const float* src = W + ((size_t)e * F_SZ + f0) * D_SZ + d0;
  int fr = t >> 2, c0 = t & 3;
#pragma unroll
  for (int c = c0; c < 16; c += 4) {
    float4 v = *(const float4*)(src + (size_t)fr * D_SZ + c * 4);
    tile[fr][c * 4 + 0] = v.x;
    tile[fr][c * 4 + 1] = v.y;
    tile[fr][c * 4 + 2] = v.z;
    tile[fr][c * 4 + 3] = v.w;
  }
  __syncthreads();
  int dr = t >> 2, cc = t & 3;
  union { unsigned short u[16]; bhalf8 v[2]; } pk;
#pragma unroll
  for (int k = 0; k < 16; ++k) pk.u[k] = (unsigned short)f2b(tile[cc * 16 + k][dr]);
  __hip_bfloat16* dst = Wt + ((size_t)e * D_SZ + d0 + dr) * F_SZ + f0 + cc * 16;
  ((bhalf8*)dst)[0] = pk.v[0];
  ((bhalf8*)dst)[1] = pk.v[1];
}

// ---------------- gather GEMM, barrier-free K-loop ----------------
// BM=32, BN=256 (full D); 4 waves 1x4, wave tile 32x64; A and B both streamed
// straight to VGPRs (no LDS => no __syncthreads => no vmcnt(0) drain).
__launch_bounds__(256, 4)
__global__ void k_gemm(const float* __restrict__ x, const __hip_bfloat16* __restrict__ Wt,
                       const float* __restrict__ bias, const int* __restrict__ counts,
                       const int* __restrict__ perm, float* __restrict__ out) {
  // flattened decode: blockIdx.x -> (expert e, mbase); full D per block
  int mt = blockIdx.x;
  int e = -1, mbase = 0, count = 0;
  {
    int acc = 0;
#pragma unroll
    for (int ee = 0; ee < E_SZ; ++ee) {
      int c = counts[ee];
      int nt = (c + 31) >> 5;
      if (e < 0 && mt < acc + nt) { e = ee; mbase = (mt - acc) * 32; count = c; }
      acc += nt;
    }
  }
  if (e < 0) return;

  int t = threadIdx.x;
  int w = t >> 6;        // wave id: n-quadrant [w*64, w*64+64)
  int lane = t & 63;
  int l15 = lane & 15;
  int q = lane >> 4;

  const int* permE = perm + e * B_SZ;
  const float* pA[2];
#pragma unroll
  for (int i = 0; i < 2; ++i) {
    int gm = mbase + i * 16 + l15;
    int src = permE[(gm < count) ? gm : mbase];   // dummy row for ragged tail
    pA[i] = x + (size_t)src * F_SZ + q * 8;       // A frag: m=lane&15, k=q*8+j
  }
  const __hip_bfloat16* pB[4];
#pragma unroll
  for (int j = 0; j < 4; ++j) {
    int n = w * 64 + j * 16 + l15;                // B frag: n=lane&15-group, k=q*8+j
    pB[j] = Wt + (size_t)(e * D_SZ + n) * F_SZ + q * 8;
  }

  fl4 zz = {0.0f, 0.0f, 0.0f, 0.0f};
  fl4 acc[2][4];
#pragma unroll
  for (int i = 0; i < 2; ++i)
#pragma unroll
    for (int j = 0; j < 4; ++j) acc[i][j] = zz;

#pragma unroll 2
  for (int k0 = 0; k0 < F_SZ; k0 += 32) {
    bhalf8 bfr[4];
#pragma unroll
    for (int j = 0; j < 4; ++j) bfr[j] = *(const bhalf8*)(pB[j] + k0);

    bhalf8 af[2];
#pragma unroll
    for (int i = 0; i < 2; ++i) {
      float4 u0 = *(const float4*)(pA[i] + k0);
      float4 u1 = *(const float4*)(pA[i] + k0 + 4);
      bhalf8 v;
      v[0] = f2b(u0.x); v[1] = f2b(u0.y); v[2] = f2b(u0.z); v[3] = f2b(u0.w);
      v[4] = f2b(u1.x); v[5] = f2b(u1.y); v[6] = f2b(u1.z); v[7] = f2b(u1.w);
      af[i] = v;
    }
#pragma unroll
    for (int i = 0; i < 2; ++i)
#pragma unroll
      for (int j = 0; j < 4; ++j)
        acc[i][j] = __builtin_amdgcn_mfma_f32_16x16x32_bf16(af[i], bfr[j], acc[i][j], 0, 0, 0);
  }

  // epilogue: C/D layout col = lane&15, row = q*4 + reg
  float bv[4];
#pragma unroll
  for (int j = 0; j < 4; ++j) bv[j] = bias[e * D_SZ + w * 64 + j * 16 + l15];

#pragma unroll
  for (int i = 0; i < 2; ++i) {
#pragma unroll
    for (int r = 0; r < 4; ++r) {
      int gm = mbase + i * 16 + q * 4 + r;
      if (gm < count) {
        int row = permE[gm];
        float* po = out + (size_t)row * D_SZ + w * 64;
#pragma unroll
        for (int j = 0; j < 4; ++j) po[j * 16 + l15] = acc[i][j][r] + bv[j];
      }
    }
  }
}

extern "C" void kernel_launch(void* const* d_in, const int* in_sizes, int n_in,
                              void* d_out, int out_size, void* d_ws, size_t ws_size,
                              hipStream_t stream) {
  const float* x = (const float*)d_in[0];
  const float* W = (const float*)d_in[1];
  const float* bias = (const float*)d_in[2];
  const int* ids = (const int*)d_in[3];
  float* out = (float*)d_out;

  char* ws = (char*)d_ws;
  int* counts = (int*)ws;                                 // 32 B
  int* perm = (int*)(ws + 256);                           // 512 KB
  __hip_bfloat16* Wt = (__hip_bfloat16*)(ws + (1 << 20)); // 8 MB

  hipMemsetAsync(counts, 0, E_SZ * sizeof(int), stream);
  k_scatter<<<B_SZ / 256, 256, 0, stream>>>(ids, counts, perm);
  k_transpose<<<dim3(F_SZ / 64, D_SZ / 64, E_SZ), 256, 0, stream>>>(W, Wt);
  k_gemm<<<GRID_G, 256, 0, stream>>>(x, Wt, bias, counts, perm, out);
}

// Round 5
// 256.932 us; speedup vs baseline: 1.9442x; 1.3315x over previous
//
#include <hip/hip_runtime.h>
#include <hip/hip_bf16.h>

#define B_SZ 16384
#define F_SZ 2048
#define D_SZ 256
#define E_SZ 8
#define GRID_G 528   // (sum_e ceil(count_e/64) <= 264) * 2 n-tiles

typedef __attribute__((ext_vector_type(8))) short bhalf8;
typedef __attribute__((ext_vector_type(4))) float fl4;

__device__ __forceinline__ short f2b(float f) {
  __hip_bfloat16 h = __float2bfloat16(f);
  union { __hip_bfloat16 h; short s; } u;
  u.h = h;
  return u.s;
}

// ---------------- bucket scatter ----------------
__global__ void k_scatter(const int* __restrict__ ids, int* __restrict__ counts,
                          int* __restrict__ perm) {
  __shared__ int lcnt[E_SZ], lbase[E_SZ];
  int t = threadIdx.x;
  if (t < E_SZ) lcnt[t] = 0;
  __syncthreads();
  int b = blockIdx.x * 256 + t;
  int e = ids[b];
  int p = atomicAdd(&lcnt[e], 1);
  __syncthreads();
  if (t < E_SZ) lbase[t] = atomicAdd(&counts[t], lcnt[t]);
  __syncthreads();
  perm[e * B_SZ + lbase[e] + p] = b;
}

// ---------------- W transpose+cast: Wt[e][d][f] = bf16(W[e][f][d]) ----------------
__global__ void k_transpose(const float* __restrict__ W, __hip_bfloat16* __restrict__ Wt) {
  __shared__ float tile[64][65];
  int e = blockIdx.z;
  int f0 = blockIdx.x * 64;
  int d0 = blockIdx.y * 64;
  int t = threadIdx.x;
  const float* src = W + ((size_t)e * F_SZ + f0) * D_SZ + d0;
  int fr = t >> 2, c0 = t & 3;
#pragma unroll
  for (int c = c0; c < 16; c += 4) {
    float4 v = *(const float4*)(src + (size_t)fr * D_SZ + c * 4);
    tile[fr][c * 4 + 0] = v.x;
    tile[fr][c * 4 + 1] = v.y;
    tile[fr][c * 4 + 2] = v.z;
    tile[fr][c * 4 + 3] = v.w;
  }
  __syncthreads();
  int dr = t >> 2, cc = t & 3;
  union { unsigned short u[16]; bhalf8 v[2]; } pk;
#pragma unroll
  for (int k = 0; k < 16; ++k) pk.u[k] = (unsigned short)f2b(tile[cc * 16 + k][dr]);
  __hip_bfloat16* dst = Wt + ((size_t)e * D_SZ + d0 + dr) * F_SZ + f0 + cc * 16;
  ((bhalf8*)dst)[0] = pk.v[0];
  ((bhalf8*)dst)[1] = pk.v[1];
}

// ---------------- async 16B global -> LDS ----------------
__device__ __forceinline__ void load_lds16(const __hip_bfloat16* g, __hip_bfloat16* l) {
  __builtin_amdgcn_global_load_lds((const __attribute__((address_space(1))) void*)g,
                                   (__attribute__((address_space(3))) void*)l, 16, 0, 0);
}

// ---------------- gather GEMM: BM=64, BN=128, BK=64, m97-style LDS staging ----------------
// 4 waves 2x2, wave tile 32x64, 16 MFMA per wave-iter.
// LDS layouts (bf16, row stride 64 elems = 128B) XOR-swizzled: 16B chunk c at
// physical (c ^ (row&7)) -> fragment ds_read_b128 is 2-way aliased (free).
__launch_bounds__(256, 2)
__global__ void k_gemm(const float* __restrict__ x, const __hip_bfloat16* __restrict__ Wt,
                       const float* __restrict__ bias, const int* __restrict__ counts,
                       const int* __restrict__ perm, float* __restrict__ out) {
  // flattened decode: blockIdx.x -> (expert e, mbase, nb)
  int id = blockIdx.x;
  int nb = (id & 1) * 128;
  int mt = id >> 1;
  int e = -1, mbase = 0, count = 0;
  {
    int acc = 0;
#pragma unroll
    for (int ee = 0; ee < E_SZ; ++ee) {
      int c = counts[ee];
      int nt = (c + 63) >> 6;
      if (e < 0 && mt < acc + nt) { e = ee; mbase = (mt - acc) * 64; count = c; }
      acc += nt;
    }
  }
  if (e < 0) return;

  __shared__ __align__(16) __hip_bfloat16 As[64 * 64];    // 8 KB
  __shared__ __align__(16) __hip_bfloat16 Bs[128 * 64];   // 16 KB

  int t = threadIdx.x;
  int w = t >> 6;
  int lane = t & 63;
  int wm = w >> 1, wn = w & 1;
  int l15 = lane & 15;
  int q = lane >> 4;

  const int* permE = perm + e * B_SZ;

  // ---- A staging setup: flat float4 f = i*256+t -> row i*16+(t>>4), k=(t&15)*4 ----
  int tr = t >> 4;      // 0..15
  int tc = t & 15;      // float4 index within row
  const float* pA[4];
  int wAo[4];           // As element offset for this thread's ds_write (8B each)
#pragma unroll
  for (int i = 0; i < 4; ++i) {
    int r = i * 16 + tr;
    int gm = mbase + r;
    int src = permE[(gm < count) ? gm : mbase];
    pA[i] = x + (size_t)src * F_SZ + tc * 4;
    int cw = tc >> 1, half = tc & 1;
    wAo[i] = r * 64 + ((cw ^ (r & 7)) * 8) + half * 4;
  }

  // ---- B staging setup: physical chunk c = i*256+t; n=c>>3; logical chunk=(c&7)^(n&7) ----
  const __hip_bfloat16* pB[4];
  __hip_bfloat16* dstB[4];
#pragma unroll
  for (int i = 0; i < 4; ++i) {
    int c = i * 256 + t;
    int n = c >> 3;
    int cl = (c & 7) ^ (n & 7);
    pB[i] = Wt + (size_t)(e * D_SZ + nb + n) * F_SZ + cl * 8;
    dstB[i] = Bs + (size_t)(i * 256 + w * 64) * 8;   // wave-uniform base (+lane*16 by HW)
  }

  // fragment read offsets (element units)
  int rAo[2][2], rBo[2][4];
#pragma unroll
  for (int ks = 0; ks < 2; ++ks) {
#pragma unroll
    for (int i = 0; i < 2; ++i) {
      int m = wm * 32 + i * 16 + l15;
      rAo[ks][i] = m * 64 + (((ks * 4 + q) ^ (m & 7)) * 8);
    }
#pragma unroll
    for (int j = 0; j < 4; ++j) {
      int n = wn * 64 + j * 16 + l15;
      rBo[ks][j] = n * 64 + (((ks * 4 + q) ^ (n & 7)) * 8);
    }
  }

  fl4 zz = {0.0f, 0.0f, 0.0f, 0.0f};
  fl4 acc[2][4];
#pragma unroll
  for (int i = 0; i < 2; ++i)
#pragma unroll
    for (int j = 0; j < 4; ++j) acc[i][j] = zz;

  for (int k0 = 0; k0 < F_SZ; k0 += 64) {
    __syncthreads();   // previous iter's fragment reads complete

    // A tile -> regs (issued first so cvt waits only on these)
    float4 av[4];
#pragma unroll
    for (int i = 0; i < 4; ++i) av[i] = *(const float4*)(pA[i] + k0);
    // B tile -> LDS via DMA
#pragma unroll
    for (int i = 0; i < 4; ++i) load_lds16(pB[i] + k0, dstB[i]);
    // cvt + write A tile
#pragma unroll
    for (int i = 0; i < 4; ++i) {
      short4 s;
      s.x = f2b(av[i].x); s.y = f2b(av[i].y);
      s.z = f2b(av[i].z); s.w = f2b(av[i].w);
      *(short4*)(As + wAo[i]) = s;
    }

    __syncthreads();   // staging complete

#pragma unroll
    for (int ks = 0; ks < 2; ++ks) {
      bhalf8 af[2], bf[4];
#pragma unroll
      for (int i = 0; i < 2; ++i) af[i] = *(const bhalf8*)(As + rAo[ks][i]);
#pragma unroll
      for (int j = 0; j < 4; ++j) bf[j] = *(const bhalf8*)(Bs + rBo[ks][j]);
#pragma unroll
      for (int i = 0; i < 2; ++i)
#pragma unroll
        for (int j = 0; j < 4; ++j)
          acc[i][j] = __builtin_amdgcn_mfma_f32_16x16x32_bf16(af[i], bf[j], acc[i][j], 0, 0, 0);
    }
  }

  // epilogue: C/D layout col = lane&15, row = q*4 + reg
  float bv[4];
#pragma unroll
  for (int j = 0; j < 4; ++j) bv[j] = bias[e * D_SZ + nb + wn * 64 + j * 16 + l15];

#pragma unroll
  for (int i = 0; i < 2; ++i) {
#pragma unroll
    for (int r = 0; r < 4; ++r) {
      int gm = mbase + wm * 32 + i * 16 + q * 4 + r;
      if (gm < count) {
        int row = permE[gm];
        float* po = out + (size_t)row * D_SZ + nb + wn * 64;
#pragma unroll
        for (int j = 0; j < 4; ++j) po[j * 16 + l15] = acc[i][j][r] + bv[j];
      }
    }
  }
}

extern "C" void kernel_launch(void* const* d_in, const int* in_sizes, int n_in,
                              void* d_out, int out_size, void* d_ws, size_t ws_size,
                              hipStream_t stream) {
  const float* x = (const float*)d_in[0];
  const float* W = (const float*)d_in[1];
  const float* bias = (const float*)d_in[2];
  const int* ids = (const int*)d_in[3];
  float* out = (float*)d_out;

  char* ws = (char*)d_ws;
  int* counts = (int*)ws;                                 // 32 B
  int* perm = (int*)(ws + 256);                           // 512 KB
  __hip_bfloat16* Wt = (__hip_bfloat16*)(ws + (1 << 20)); // 8 MB

  hipMemsetAsync(counts, 0, E_SZ * sizeof(int), stream);
  k_scatter<<<B_SZ / 256, 256, 0, stream>>>(ids, counts, perm);
  k_transpose<<<dim3(F_SZ / 64, D_SZ / 64, E_SZ), 256, 0, stream>>>(W, Wt);
  k_gemm<<<GRID_G, 256, 0, stream>>>(x, Wt, bias, counts, perm, out);
}